// Round 23
// baseline (645.053 us; speedup 1.0000x reference)
//
#include <hip/hip_runtime.h>
#include <math.h>

#define IMG_H 512
#define IMG_W 512
#define N_IMG 96            // 32 * 3
#define TW 32               // tile width (output cols)
#define TH 118              // tile height -> NUNITS = (118+10)*8 = 1024 EXACTLY
#define KS 11
#define IN_ROWS_MAX 138     // LDS pad: stage-2 rg=31 reads rows up to 137
#define STRIDE 33           // LDS row stride in float2 units
#define PLANE (IN_ROWS_MAX * STRIDE)   // 4554 float2 (72.9 KB total planes)
#define TILES_Y 5           // 4 full 118-row tiles + 40-row tail
#define NBLOCKS (N_IMG * (IMG_W / TW) * TILES_Y)   // 96*16*5 = 7680
#define TOTAL_N 25165824.0  // 32*3*512*512

// Round-21 (2nd resubmit; two infra failures in a row): r18 structure
// (best: 117us, 1024-thr blocks, one tile/block; persistence abandoned
// after r10/r19/r20 all failed, r20 = spill 100MB) with the LAST clean
// fix: stage-1 LOAD BALANCE.
// r18: NUNITS=1104 > 1024 threads -> waves 0-1 did TWO conv units while
// waves 2-15 idled at the barrier (2x stage-1 critical path).
// TH=118 makes NUNITS=1024 exactly: one unit per thread, zero stragglers.
// Image column = 5 tile-rows (4x118 + 40-row tail). Tail guards:
//  - stage 1: u < nunits = (tileH+10)*8
//  - stage 2: contribution only if row < tileH. Valid outputs only ever
//    read H-rows stage 1 wrote; garbage rows feed only discarded
//    accumulators (never touch lsum).
// LDS 72.9KB -> 2 blocks/CU (proven co-resident, r18). (1024,8): VGPR cap
// 64, kernel needs ~32, no loop-carried state -> no r20-style spill.

#define GW(j) g6[(j) <= 5 ? (j) : 10 - (j)]

__global__ __launch_bounds__(1024, 8) void ssim_tile_kernel(
    const float* __restrict__ pred, const float* __restrict__ targ,
    const float* __restrict__ k2d, float* __restrict__ partial)
{
    __shared__ float2 Hu[PLANE];
    __shared__ float2 Hv[PLANE];
    __shared__ float wsum[16];

    const int tid = threadIdx.x;
    const int bid = blockIdx.x;
    const int img = bid / 80;              // 80 tiles per image (16 strips x 5)
    const int rem = bid - img * 80;
    const int tx  = rem / 5;               // 0..15
    const int ty  = rem - tx * 5;          // 0..4
    const int y0  = ty * TH;
    const int x0  = tx * TW;
    const int tileH  = min(TH, IMG_H - y0);        // 118 or 40
    const int nunits = (tileH + 10) * 8;           // 1024 or 400

    // exact 1D gaussian from the 2D kernel row 5: k2d[5][j] = g5*g[j]; symmetric
    float g6[6];
    {
        const float inv = rsqrtf(k2d[5 * KS + 5]);
        #pragma unroll
        for (int j = 0; j < 6; ++j) g6[j] = k2d[5 * KS + j] * inv;
    }

    const float* __restrict__ Pimg = pred + (size_t)img * (IMG_H * IMG_W);
    const float* __restrict__ Timg = targ + (size_t)img * (IMG_H * IMG_W);

    // ---- stage 1: horizontal 11-tap on u,v,u^2,v^2 -> packed LDS planes ----
    // exactly one unit per thread for full tiles
    if (tid < nunits) {
        const int r    = tid >> 3;         // 0..127 (row of H planes)
        const int cg   = tid & 7;          // 0..7
        const int gr   = y0 - 5 + r;
        const int col0 = x0 + (cg << 2) - 8;   // 16B-aligned window start
        const bool rowok = ((unsigned)gr < (unsigned)IMG_H);
        const float* rowP = Pimg + (size_t)(rowok ? gr : 0) * IMG_W;
        const float* rowT = Timg + (size_t)(rowok ? gr : 0) * IMG_W;

        // used window elems are 3..16 -> uw/vw[0..13]
        float uw[14], vw[14];
        if (rowok && col0 >= 0 && col0 + 20 <= IMG_W) {
            #pragma unroll
            for (int q = 0; q < 5; ++q) {
                const float4 vp = *(const float4*)(rowP + col0 + 4 * q);
                const float4 vt = *(const float4*)(rowT + col0 + 4 * q);
                const float pe[4] = {vp.x, vp.y, vp.z, vp.w};
                const float te[4] = {vt.x, vt.y, vt.z, vt.w};
                #pragma unroll
                for (int e = 0; e < 4; ++e) {
                    const int ge = 4 * q + e;          // compile-time
                    if (ge >= 3 && ge <= 16) {
                        uw[ge - 3] = pe[e] + te[e];
                        vw[ge - 3] = pe[e] - te[e];
                    }
                }
            }
        } else {
            #pragma unroll
            for (int e = 3; e <= 16; ++e) {
                const int c  = col0 + e;
                const int cc = min(max(c, 0), IMG_W - 1);
                const bool ok = rowok && (c >= 0) && (c < IMG_W);
                const float pv = rowP[cc];
                const float tv = rowT[cc];
                uw[e - 3] = ok ? (pv + tv) : 0.0f;
                vw[e - 3] = ok ? (pv - tv) : 0.0f;
            }
        }

        const int wb = r * STRIDE + (cg << 2);

        // u-maps: mu conv, square in place, second-moment conv, write
        {
            float au[4], auu[4];
            #pragma unroll
            for (int k = 0; k < 4; ++k) { au[k] = 0.f; }
            #pragma unroll
            for (int k = 0; k < 4; ++k) {
                #pragma unroll
                for (int j = 0; j < KS; ++j)
                    au[k] = fmaf(GW(j), uw[k + j], au[k]);
            }
            #pragma unroll
            for (int i = 0; i < 14; ++i) uw[i] *= uw[i];
            #pragma unroll
            for (int k = 0; k < 4; ++k) { auu[k] = 0.f; }
            #pragma unroll
            for (int k = 0; k < 4; ++k) {
                #pragma unroll
                for (int j = 0; j < KS; ++j)
                    auu[k] = fmaf(GW(j), uw[k + j], auu[k]);
            }
            #pragma unroll
            for (int e = 0; e < 4; ++e)
                Hu[wb + e] = make_float2(au[e], auu[e]);
        }
        // v-maps
        {
            float av[4], avv[4];
            #pragma unroll
            for (int k = 0; k < 4; ++k) { av[k] = 0.f; }
            #pragma unroll
            for (int k = 0; k < 4; ++k) {
                #pragma unroll
                for (int j = 0; j < KS; ++j)
                    av[k] = fmaf(GW(j), vw[k + j], av[k]);
            }
            #pragma unroll
            for (int i = 0; i < 14; ++i) vw[i] *= vw[i];
            #pragma unroll
            for (int k = 0; k < 4; ++k) { avv[k] = 0.f; }
            #pragma unroll
            for (int k = 0; k < 4; ++k) {
                #pragma unroll
                for (int j = 0; j < KS; ++j)
                    avv[k] = fmaf(GW(j), vw[k + j], avv[k]);
            }
            #pragma unroll
            for (int e = 0; e < 4; ++e)
                Hv[wb + e] = make_float2(av[e], avv[e]);
        }
    }
    __syncthreads();

    // ---- stage 2: vertical 11-tap (streaming from LDS) + SSIM formula ----
    const int col = tid & 31;
    const int rg  = tid >> 5;          // 0..31, output rows rg*4 .. rg*4+3

    const float C1 = 1.0e-4f;   // (0.01*1)^2
    const float C2 = 9.0e-4f;   // (0.03*1)^2
    float lsum = 0.0f;

    {
        float sau[4], sav[4], sauu[4], savv[4];
        #pragma unroll
        for (int k = 0; k < 4; ++k) {
            sau[k] = 0.f; sav[k] = 0.f; sauu[k] = 0.f; savv[k] = 0.f;
        }

        #pragma unroll
        for (int i = 0; i < 14; ++i) {
            const int idx = (rg * 4 + i) * STRIDE + col;
            const float2 hu = Hu[idx];
            const float2 hv = Hv[idx];
            #pragma unroll
            for (int k = 0; k < 4; ++k) {
                const int j = i - k;                   // compile-time tap
                if (j >= 0 && j < KS) {
                    sau [k] = fmaf(GW(j), hu.x, sau [k]);
                    sauu[k] = fmaf(GW(j), hu.y, sauu[k]);
                    sav [k] = fmaf(GW(j), hv.x, sav [k]);
                    savv[k] = fmaf(GW(j), hv.y, savv[k]);
                }
            }
        }

        #pragma unroll
        for (int k = 0; k < 4; ++k) {
            const int row = rg * 4 + k;
            if (row < tileH) {                  // tail-tile validity guard
                const float u2 = sau[k] * sau[k];   // muu^2
                const float v2 = sav[k] * sav[k];   // muv^2
                const float A  = u2 - v2;           // 4*mux*muy
                const float B  = u2 + v2;           // 2*(mux^2+muy^2)
                const float Cd = sauu[k] - savv[k]; // 4*conv(xy)
                const float Cs = sauu[k] + savv[k]; // 2*(conv(x2)+conv(y2))
                const float num1 = fmaf(0.5f, A, C1);
                const float den1 = fmaf(0.5f, B, C1);
                const float num2 = fmaf(0.5f, Cd - A, C2);
                const float den2 = fmaf(0.5f, Cs - B, C2);
                lsum = fmaf(num1 * num2, __builtin_amdgcn_rcpf(den1 * den2), lsum);
            }
        }
    }

    // ---- block reduction (16 waves) ----
    #pragma unroll
    for (int off = 32; off > 0; off >>= 1)
        lsum += __shfl_down(lsum, off, 64);

    const int lane = tid & 63;
    const int wid  = tid >> 6;         // 0..15
    if (lane == 0) wsum[wid] = lsum;
    __syncthreads();
    if (tid == 0) {
        float s = 0.0f;
        #pragma unroll
        for (int w = 0; w < 16; ++w) s += wsum[w];
        partial[bid] = s;
    }
}

// ---------------- final reduction ----------------
__global__ __launch_bounds__(1024) void ssim_reduce_kernel(
    const float* __restrict__ partial, int n, float* __restrict__ out)
{
    const int tid = threadIdx.x;
    double s = 0.0;
    for (int i = tid; i < n; i += 1024) s += (double)partial[i];

    #pragma unroll
    for (int off = 32; off > 0; off >>= 1)
        s += __shfl_down(s, off, 64);

    __shared__ double dsum[16];
    const int lane = tid & 63;
    const int wid  = tid >> 6;
    if (lane == 0) dsum[wid] = s;
    __syncthreads();
    if (tid == 0) {
        double total = 0.0;
        #pragma unroll
        for (int w = 0; w < 16; ++w) total += dsum[w];
        out[0] = (float)(1.0 - total / TOTAL_N);
    }
}

extern "C" void kernel_launch(void* const* d_in, const int* in_sizes, int n_in,
                              void* d_out, int out_size, void* d_ws, size_t ws_size,
                              hipStream_t stream) {
    const float* pred = (const float*)d_in[0];
    const float* targ = (const float*)d_in[1];
    const float* k2d  = (const float*)d_in[2];
    float* out = (float*)d_out;
    float* ws  = (float*)d_ws;   // NBLOCKS partial sums

    ssim_tile_kernel<<<NBLOCKS, 1024, 0, stream>>>(pred, targ, k2d, ws);
    ssim_reduce_kernel<<<1, 1024, 0, stream>>>(ws, NBLOCKS, out);
}

// Round 24
// 639.384 us; speedup vs baseline: 1.0089x; 1.0089x over previous
//
#include <hip/hip_runtime.h>
#include <math.h>

#define IMG_H 512
#define IMG_W 512
#define N_IMG 96            // 32 * 3
#define TW 32               // tile width (output cols)
#define TH 118              // tile height -> NUNITS = (118+10)*8 = 1024 EXACTLY
#define KS 11
#define IN_ROWS_MAX 138     // LDS pad: stage-2 rg=31 reads rows up to 137
#define STRIDE 33           // LDS row stride in float2 units
#define PLANE (IN_ROWS_MAX * STRIDE)   // 4554 float2 (72.9 KB total planes)
#define TILES_Y 5           // 4 full 118-row tiles + 40-row tail
#define NBLOCKS (N_IMG * (IMG_W / TW) * TILES_Y)   // 96*16*5 = 7680
#define TOTAL_N 25165824.0  // 32*3*512*512

// Round-24: r23 minus the dispatch-order bug.
// r23 counters: FETCH 284MB -> 1.5GB, dur 645us, WRITE ~1MB (no spill),
// occ 89%. Cause: rem decomposition tx=rem/5, ty=rem%5 made ty FASTEST ->
// consecutive blocks were vertical neighbors; the horizontal neighbors that
// share row-cachelines (128B line = 32 floats, read by tx-1/tx/tx+1 via
// halos) were 5 bids apart -> different XCDs -> ~5x L2 fill traffic.
// Fix: tx = rem & 15 (fastest), ty = rem >> 4 -- exactly r18's order
// (which measured 284MB). Keep TH=118 load balance (1 conv unit/thread,
// zero stragglers; occupancy measured 89% at r23).
// LDS 72.9KB -> 2 blocks/CU. (1024,8): VGPR cap 64, kernel needs 32.

#define GW(j) g6[(j) <= 5 ? (j) : 10 - (j)]

__global__ __launch_bounds__(1024, 8) void ssim_tile_kernel(
    const float* __restrict__ pred, const float* __restrict__ targ,
    const float* __restrict__ k2d, float* __restrict__ partial)
{
    __shared__ float2 Hu[PLANE];
    __shared__ float2 Hv[PLANE];
    __shared__ float wsum[16];

    const int tid = threadIdx.x;
    const int bid = blockIdx.x;
    const int img = bid / 80;              // 80 tiles per image (5 ty x 16 tx)
    const int rem = bid - img * 80;
    const int tx  = rem & 15;              // FASTEST -> horizontal neighbors adjacent
    const int ty  = rem >> 4;              // 0..4
    const int y0  = ty * TH;
    const int x0  = tx * TW;
    const int tileH  = min(TH, IMG_H - y0);        // 118 or 40
    const int nunits = (tileH + 10) * 8;           // 1024 or 400

    // exact 1D gaussian from the 2D kernel row 5: k2d[5][j] = g5*g[j]; symmetric
    float g6[6];
    {
        const float inv = rsqrtf(k2d[5 * KS + 5]);
        #pragma unroll
        for (int j = 0; j < 6; ++j) g6[j] = k2d[5 * KS + j] * inv;
    }

    const float* __restrict__ Pimg = pred + (size_t)img * (IMG_H * IMG_W);
    const float* __restrict__ Timg = targ + (size_t)img * (IMG_H * IMG_W);

    // ---- stage 1: horizontal 11-tap on u,v,u^2,v^2 -> packed LDS planes ----
    // exactly one unit per thread for full tiles
    if (tid < nunits) {
        const int r    = tid >> 3;         // 0..127 (row of H planes)
        const int cg   = tid & 7;          // 0..7
        const int gr   = y0 - 5 + r;
        const int col0 = x0 + (cg << 2) - 8;   // 16B-aligned window start
        const bool rowok = ((unsigned)gr < (unsigned)IMG_H);
        const float* rowP = Pimg + (size_t)(rowok ? gr : 0) * IMG_W;
        const float* rowT = Timg + (size_t)(rowok ? gr : 0) * IMG_W;

        // used window elems are 3..16 -> uw/vw[0..13]
        float uw[14], vw[14];
        if (rowok && col0 >= 0 && col0 + 20 <= IMG_W) {
            #pragma unroll
            for (int q = 0; q < 5; ++q) {
                const float4 vp = *(const float4*)(rowP + col0 + 4 * q);
                const float4 vt = *(const float4*)(rowT + col0 + 4 * q);
                const float pe[4] = {vp.x, vp.y, vp.z, vp.w};
                const float te[4] = {vt.x, vt.y, vt.z, vt.w};
                #pragma unroll
                for (int e = 0; e < 4; ++e) {
                    const int ge = 4 * q + e;          // compile-time
                    if (ge >= 3 && ge <= 16) {
                        uw[ge - 3] = pe[e] + te[e];
                        vw[ge - 3] = pe[e] - te[e];
                    }
                }
            }
        } else {
            #pragma unroll
            for (int e = 3; e <= 16; ++e) {
                const int c  = col0 + e;
                const int cc = min(max(c, 0), IMG_W - 1);
                const bool ok = rowok && (c >= 0) && (c < IMG_W);
                const float pv = rowP[cc];
                const float tv = rowT[cc];
                uw[e - 3] = ok ? (pv + tv) : 0.0f;
                vw[e - 3] = ok ? (pv - tv) : 0.0f;
            }
        }

        const int wb = r * STRIDE + (cg << 2);

        // u-maps: mu conv, square in place, second-moment conv, write
        {
            float au[4], auu[4];
            #pragma unroll
            for (int k = 0; k < 4; ++k) { au[k] = 0.f; }
            #pragma unroll
            for (int k = 0; k < 4; ++k) {
                #pragma unroll
                for (int j = 0; j < KS; ++j)
                    au[k] = fmaf(GW(j), uw[k + j], au[k]);
            }
            #pragma unroll
            for (int i = 0; i < 14; ++i) uw[i] *= uw[i];
            #pragma unroll
            for (int k = 0; k < 4; ++k) { auu[k] = 0.f; }
            #pragma unroll
            for (int k = 0; k < 4; ++k) {
                #pragma unroll
                for (int j = 0; j < KS; ++j)
                    auu[k] = fmaf(GW(j), uw[k + j], auu[k]);
            }
            #pragma unroll
            for (int e = 0; e < 4; ++e)
                Hu[wb + e] = make_float2(au[e], auu[e]);
        }
        // v-maps
        {
            float av[4], avv[4];
            #pragma unroll
            for (int k = 0; k < 4; ++k) { av[k] = 0.f; }
            #pragma unroll
            for (int k = 0; k < 4; ++k) {
                #pragma unroll
                for (int j = 0; j < KS; ++j)
                    av[k] = fmaf(GW(j), vw[k + j], av[k]);
            }
            #pragma unroll
            for (int i = 0; i < 14; ++i) vw[i] *= vw[i];
            #pragma unroll
            for (int k = 0; k < 4; ++k) { avv[k] = 0.f; }
            #pragma unroll
            for (int k = 0; k < 4; ++k) {
                #pragma unroll
                for (int j = 0; j < KS; ++j)
                    avv[k] = fmaf(GW(j), vw[k + j], avv[k]);
            }
            #pragma unroll
            for (int e = 0; e < 4; ++e)
                Hv[wb + e] = make_float2(av[e], avv[e]);
        }
    }
    __syncthreads();

    // ---- stage 2: vertical 11-tap (streaming from LDS) + SSIM formula ----
    const int col = tid & 31;
    const int rg  = tid >> 5;          // 0..31, output rows rg*4 .. rg*4+3

    const float C1 = 1.0e-4f;   // (0.01*1)^2
    const float C2 = 9.0e-4f;   // (0.03*1)^2
    float lsum = 0.0f;

    {
        float sau[4], sav[4], sauu[4], savv[4];
        #pragma unroll
        for (int k = 0; k < 4; ++k) {
            sau[k] = 0.f; sav[k] = 0.f; sauu[k] = 0.f; savv[k] = 0.f;
        }

        #pragma unroll
        for (int i = 0; i < 14; ++i) {
            const int idx = (rg * 4 + i) * STRIDE + col;
            const float2 hu = Hu[idx];
            const float2 hv = Hv[idx];
            #pragma unroll
            for (int k = 0; k < 4; ++k) {
                const int j = i - k;                   // compile-time tap
                if (j >= 0 && j < KS) {
                    sau [k] = fmaf(GW(j), hu.x, sau [k]);
                    sauu[k] = fmaf(GW(j), hu.y, sauu[k]);
                    sav [k] = fmaf(GW(j), hv.x, sav [k]);
                    savv[k] = fmaf(GW(j), hv.y, savv[k]);
                }
            }
        }

        #pragma unroll
        for (int k = 0; k < 4; ++k) {
            const int row = rg * 4 + k;
            if (row < tileH) {                  // tail-tile validity guard
                const float u2 = sau[k] * sau[k];   // muu^2
                const float v2 = sav[k] * sav[k];   // muv^2
                const float A  = u2 - v2;           // 4*mux*muy
                const float B  = u2 + v2;           // 2*(mux^2+muy^2)
                const float Cd = sauu[k] - savv[k]; // 4*conv(xy)
                const float Cs = sauu[k] + savv[k]; // 2*(conv(x2)+conv(y2))
                const float num1 = fmaf(0.5f, A, C1);
                const float den1 = fmaf(0.5f, B, C1);
                const float num2 = fmaf(0.5f, Cd - A, C2);
                const float den2 = fmaf(0.5f, Cs - B, C2);
                lsum = fmaf(num1 * num2, __builtin_amdgcn_rcpf(den1 * den2), lsum);
            }
        }
    }

    // ---- block reduction (16 waves) ----
    #pragma unroll
    for (int off = 32; off > 0; off >>= 1)
        lsum += __shfl_down(lsum, off, 64);

    const int lane = tid & 63;
    const int wid  = tid >> 6;         // 0..15
    if (lane == 0) wsum[wid] = lsum;
    __syncthreads();
    if (tid == 0) {
        float s = 0.0f;
        #pragma unroll
        for (int w = 0; w < 16; ++w) s += wsum[w];
        partial[bid] = s;
    }
}

// ---------------- final reduction ----------------
__global__ __launch_bounds__(1024) void ssim_reduce_kernel(
    const float* __restrict__ partial, int n, float* __restrict__ out)
{
    const int tid = threadIdx.x;
    double s = 0.0;
    for (int i = tid; i < n; i += 1024) s += (double)partial[i];

    #pragma unroll
    for (int off = 32; off > 0; off >>= 1)
        s += __shfl_down(s, off, 64);

    __shared__ double dsum[16];
    const int lane = tid & 63;
    const int wid  = tid >> 6;
    if (lane == 0) dsum[wid] = s;
    __syncthreads();
    if (tid == 0) {
        double total = 0.0;
        #pragma unroll
        for (int w = 0; w < 16; ++w) total += dsum[w];
        out[0] = (float)(1.0 - total / TOTAL_N);
    }
}

extern "C" void kernel_launch(void* const* d_in, const int* in_sizes, int n_in,
                              void* d_out, int out_size, void* d_ws, size_t ws_size,
                              hipStream_t stream) {
    const float* pred = (const float*)d_in[0];
    const float* targ = (const float*)d_in[1];
    const float* k2d  = (const float*)d_in[2];
    float* out = (float*)d_out;
    float* ws  = (float*)d_ws;   // NBLOCKS partial sums

    ssim_tile_kernel<<<NBLOCKS, 1024, 0, stream>>>(pred, targ, k2d, ws);
    ssim_reduce_kernel<<<1, 1024, 0, stream>>>(ws, NBLOCKS, out);
}

// Round 27
// 98.676 us; speedup vs baseline: 6.5371x; 6.4796x over previous
//
#include <hip/hip_runtime.h>
#include <math.h>

#define IMG_H 512
#define IMG_W 512
#define N_IMG 96            // 32 * 3
#define TW 32               // tile width (output cols)
#define TH 128              // tile height (output rows) -- r18 compile-time geometry
#define KS 11
#define IN_ROWS 138         // TH + 10
#define NUNITS (IN_ROWS * 8)    // 1104 horizontal-conv units (4 px each)
#define STRIDE 33           // LDS row stride in float2 units
#define PLANE (IN_ROWS * STRIDE)   // 4554 float2
#define NBLOCKS (N_IMG * (IMG_W / TW) * (IMG_H / TH))   // 96*16*4 = 6144
#define TOTAL_N 25165824.0  // 32*3*512*512

// Round-25 (3rd submit; two infra failures): EXACT r18 kernel (117us proven;
// VGPR 32, no spill, occ 65-68%) + XCD-aware block swizzle.
// r23/r24 lesson (ERRATA): TH=118's runtime tileH/nunits put stage 1 under a
// runtime-divergent branch -> allocator collapse -> 1.1GB scratch WRITE
// (misread as 1.1MB in r23; r24 falsified the dispatch-order theory).
// Compile-time geometry is mandatory. TH=118 abandoned.
// Swizzle: swz=(bid&7)*768+(bid>>3), bijective (6144=8*768). At any moment
// each XCD's ~64 in-flight blocks cover ~ONE complete image (2MB < 4MB L2):
// halo re-reads (10/138 rows V, 8/40 cols H; most cachelines shared 2-3x)
// become local-L2 hits (~200cy) instead of HBM (~900cy). Kernel is
// latency-bound (true VALU ~33%) -> attacks the stall directly.

#define GW(j) g6[(j) <= 5 ? (j) : 10 - (j)]

__global__ __launch_bounds__(1024, 8) void ssim_tile_kernel(
    const float* __restrict__ pred, const float* __restrict__ targ,
    const float* __restrict__ k2d, float* __restrict__ partial)
{
    __shared__ float2 Hu[PLANE];
    __shared__ float2 Hv[PLANE];
    __shared__ float wsum[16];

    const int tid = threadIdx.x;
    const int bid = blockIdx.x;
    // XCD-aware swizzle: XCD x (= bid&7) owns a contiguous 768-block range
    // = 12 complete images; concurrent blocks per XCD ~= one image.
    const int swz = (bid & 7) * 768 + (bid >> 3);
    const int img = swz >> 6;          // 64 tiles per image
    const int tin = swz & 63;
    const int ty  = tin >> 4;          // 0..3
    const int tx  = tin & 15;          // 0..15 (fastest -> H-neighbors adjacent)
    const int y0  = ty * TH;
    const int x0  = tx * TW;

    // exact 1D gaussian from the 2D kernel row 5: k2d[5][j] = g5*g[j]; symmetric
    float g6[6];
    {
        const float inv = rsqrtf(k2d[5 * KS + 5]);
        #pragma unroll
        for (int j = 0; j < 6; ++j) g6[j] = k2d[5 * KS + j] * inv;
    }

    const float* __restrict__ Pimg = pred + (size_t)img * (IMG_H * IMG_W);
    const float* __restrict__ Timg = targ + (size_t)img * (IMG_H * IMG_W);

    // ---- stage 1: horizontal 11-tap on u,v,u^2,v^2 -> packed LDS planes ----
    #pragma unroll
    for (int b = 0; b < 2; ++b) {
        const int u = tid + (b << 10);         // b=0: all 1024; b=1: tid<80
        if (u < NUNITS) {
            const int r    = u >> 3;           // 0..137
            const int cg   = u & 7;            // 0..7
            const int gr   = y0 - 5 + r;
            const int col0 = x0 + (cg << 2) - 8;   // 16B-aligned window start
            const bool rowok = ((unsigned)gr < (unsigned)IMG_H);
            const float* rowP = Pimg + (size_t)(rowok ? gr : 0) * IMG_W;
            const float* rowT = Timg + (size_t)(rowok ? gr : 0) * IMG_W;

            // used window elems are 3..16 -> uw/vw[0..13]
            float uw[14], vw[14];
            if (rowok && col0 >= 0 && col0 + 20 <= IMG_W) {
                #pragma unroll
                for (int q = 0; q < 5; ++q) {
                    const float4 vp = *(const float4*)(rowP + col0 + 4 * q);
                    const float4 vt = *(const float4*)(rowT + col0 + 4 * q);
                    const float pe[4] = {vp.x, vp.y, vp.z, vp.w};
                    const float te[4] = {vt.x, vt.y, vt.z, vt.w};
                    #pragma unroll
                    for (int e = 0; e < 4; ++e) {
                        const int ge = 4 * q + e;          // compile-time
                        if (ge >= 3 && ge <= 16) {
                            uw[ge - 3] = pe[e] + te[e];
                            vw[ge - 3] = pe[e] - te[e];
                        }
                    }
                }
            } else {
                #pragma unroll
                for (int e = 3; e <= 16; ++e) {
                    const int c  = col0 + e;
                    const int cc = min(max(c, 0), IMG_W - 1);
                    const bool ok = rowok && (c >= 0) && (c < IMG_W);
                    const float pv = rowP[cc];
                    const float tv = rowT[cc];
                    uw[e - 3] = ok ? (pv + tv) : 0.0f;
                    vw[e - 3] = ok ? (pv - tv) : 0.0f;
                }
            }

            const int wb = r * STRIDE + (cg << 2);

            // u-maps: mu conv, square in place, second-moment conv, write
            {
                float au[4], auu[4];
                #pragma unroll
                for (int k = 0; k < 4; ++k) { au[k] = 0.f; }
                #pragma unroll
                for (int k = 0; k < 4; ++k) {
                    #pragma unroll
                    for (int j = 0; j < KS; ++j)
                        au[k] = fmaf(GW(j), uw[k + j], au[k]);
                }
                #pragma unroll
                for (int i = 0; i < 14; ++i) uw[i] *= uw[i];
                #pragma unroll
                for (int k = 0; k < 4; ++k) { auu[k] = 0.f; }
                #pragma unroll
                for (int k = 0; k < 4; ++k) {
                    #pragma unroll
                    for (int j = 0; j < KS; ++j)
                        auu[k] = fmaf(GW(j), uw[k + j], auu[k]);
                }
                #pragma unroll
                for (int e = 0; e < 4; ++e)
                    Hu[wb + e] = make_float2(au[e], auu[e]);
            }
            // v-maps
            {
                float av[4], avv[4];
                #pragma unroll
                for (int k = 0; k < 4; ++k) { av[k] = 0.f; }
                #pragma unroll
                for (int k = 0; k < 4; ++k) {
                    #pragma unroll
                    for (int j = 0; j < KS; ++j)
                        av[k] = fmaf(GW(j), vw[k + j], av[k]);
                }
                #pragma unroll
                for (int i = 0; i < 14; ++i) vw[i] *= vw[i];
                #pragma unroll
                for (int k = 0; k < 4; ++k) { avv[k] = 0.f; }
                #pragma unroll
                for (int k = 0; k < 4; ++k) {
                    #pragma unroll
                    for (int j = 0; j < KS; ++j)
                        avv[k] = fmaf(GW(j), vw[k + j], avv[k]);
                }
                #pragma unroll
                for (int e = 0; e < 4; ++e)
                    Hv[wb + e] = make_float2(av[e], avv[e]);
            }
        }
    }
    __syncthreads();

    // ---- stage 2: vertical 11-tap (streaming from LDS) + SSIM formula ----
    const int col = tid & 31;
    const int rg  = tid >> 5;          // 0..31, rows rg*4 .. rg*4+3

    const float C1 = 1.0e-4f;   // (0.01*1)^2
    const float C2 = 9.0e-4f;   // (0.03*1)^2
    float lsum = 0.0f;

    {
        float sau[4], sav[4], sauu[4], savv[4];
        #pragma unroll
        for (int k = 0; k < 4; ++k) {
            sau[k] = 0.f; sav[k] = 0.f; sauu[k] = 0.f; savv[k] = 0.f;
        }

        #pragma unroll
        for (int i = 0; i < 14; ++i) {
            const int idx = (rg * 4 + i) * STRIDE + col;
            const float2 hu = Hu[idx];
            const float2 hv = Hv[idx];
            #pragma unroll
            for (int k = 0; k < 4; ++k) {
                const int j = i - k;                   // compile-time tap
                if (j >= 0 && j < KS) {
                    sau [k] = fmaf(GW(j), hu.x, sau [k]);
                    sauu[k] = fmaf(GW(j), hu.y, sauu[k]);
                    sav [k] = fmaf(GW(j), hv.x, sav [k]);
                    savv[k] = fmaf(GW(j), hv.y, savv[k]);
                }
            }
        }

        #pragma unroll
        for (int k = 0; k < 4; ++k) {
            const float u2 = sau[k] * sau[k];   // muu^2
            const float v2 = sav[k] * sav[k];   // muv^2
            const float A  = u2 - v2;           // 4*mux*muy
            const float B  = u2 + v2;           // 2*(mux^2+muy^2)
            const float Cd = sauu[k] - savv[k]; // 4*conv(xy)
            const float Cs = sauu[k] + savv[k]; // 2*(conv(x^2)+conv(y^2))
            const float num1 = fmaf(0.5f, A, C1);        // 2 mux muy + C1
            const float den1 = fmaf(0.5f, B, C1);        // mux^2+muy^2 + C1
            const float num2 = fmaf(0.5f, Cd - A, C2);   // 2 sigma_xy + C2
            const float den2 = fmaf(0.5f, Cs - B, C2);   // sx2+sy2 + C2
            lsum = fmaf(num1 * num2, __builtin_amdgcn_rcpf(den1 * den2), lsum);
        }
    }

    // ---- block reduction (16 waves) ----
    #pragma unroll
    for (int off = 32; off > 0; off >>= 1)
        lsum += __shfl_down(lsum, off, 64);

    const int lane = tid & 63;
    const int wid  = tid >> 6;         // 0..15
    if (lane == 0) wsum[wid] = lsum;
    __syncthreads();
    if (tid == 0) {
        float s = 0.0f;
        #pragma unroll
        for (int w = 0; w < 16; ++w) s += wsum[w];
        partial[bid] = s;
    }
}

// ---------------- final reduction ----------------
__global__ __launch_bounds__(1024) void ssim_reduce_kernel(
    const float* __restrict__ partial, int n, float* __restrict__ out)
{
    const int tid = threadIdx.x;
    double s = 0.0;
    for (int i = tid; i < n; i += 1024) s += (double)partial[i];

    #pragma unroll
    for (int off = 32; off > 0; off >>= 1)
        s += __shfl_down(s, off, 64);

    __shared__ double dsum[16];
    const int lane = tid & 63;
    const int wid  = tid >> 6;
    if (lane == 0) dsum[wid] = s;
    __syncthreads();
    if (tid == 0) {
        double total = 0.0;
        #pragma unroll
        for (int w = 0; w < 16; ++w) total += dsum[w];
        out[0] = (float)(1.0 - total / TOTAL_N);
    }
}

extern "C" void kernel_launch(void* const* d_in, const int* in_sizes, int n_in,
                              void* d_out, int out_size, void* d_ws, size_t ws_size,
                              hipStream_t stream) {
    const float* pred = (const float*)d_in[0];
    const float* targ = (const float*)d_in[1];
    const float* k2d  = (const float*)d_in[2];
    float* out = (float*)d_out;
    float* ws  = (float*)d_ws;   // NBLOCKS partial sums

    ssim_tile_kernel<<<NBLOCKS, 1024, 0, stream>>>(pred, targ, k2d, ws);
    ssim_reduce_kernel<<<1, 1024, 0, stream>>>(ws, NBLOCKS, out);
}